// Round 6
// baseline (259.149 us; speedup 1.0000x reference)
//
#include <hip/hip_runtime.h>

#define N_NODES 100000
#define N_EDGES 3200000
#define CH 256

#define GRID_QK 1563     // 64 nodes/block
#define GRID_POOL 512
#define YCOPY 16

// partition + dense-consume geometry
#define NR 4             // node ranges
#define RANGE 25000      // nodes per range; consumer LDS acc = 100000 B dynamic
#define SL 64            // consumer slices per range; grid_acc = NR*SL = 256
#define EPB_P 12500      // edges per k_part block; 256*12500 = N_EDGES exact
#define GRID_P 256
#define CAP 3600         // per-range LDS segment capacity in k_part (mean 3125, +10 sigma)
#define SCAP 850000      // per-range global stream capacity (mean 800K, +64 sigma)
#define GP 391           // ceil(N_NODES/256) fold blocks -> ptot entries

#define LDSP_FLOATS (6 * CAP + 8)        // lex[4*CAP] + lrow(u16[4*CAP] = 2*CAP fl) + cnt/gbase
#define LDSP_BYTES  (LDSP_FLOATS * 4)    // 86,432 B
#define LDSA_BYTES  (RANGE * 4)          // 100,000 B

// ---- ws layout (float offsets) ----
#define OFF_TOTAL 0
#define OFF_PTOT  16        // 512 (only GP used)
#define OFF_YU16  528       // 4096
#define OFF_GCNT  4624      // 4 ints
#define OFF_Q     4640      // 100000
#define OFF_K     104640    // 100000
#define OFF_AWU   204640    // 100000
#define OFF_EXS   304640    // NR*SCAP floats = 3,400,000
#define OFF_RWS   3704640   // NR*SCAP u16 = 1,700,000 floats
#define OFF_PART  5404640   // NR*SL*RANGE = 6,400,000 floats
// end = 11,804,640 floats ~= 47.2 MiB (ws ~= 400 MB per R4 fill counters)

// q[n]=x[n,:].Wq+bq, k[n]=x[n,:].Wk+bk. 16-lane dot groups, 4 shuffle levels.
// Also zeroes yu16 + gcnt for the later kernels.
__global__ __launch_bounds__(256) void k_qk(const float* __restrict__ x,
                                            const float* __restrict__ Wq,
                                            const float* __restrict__ bq,
                                            const float* __restrict__ Wk,
                                            const float* __restrict__ bk,
                                            float* __restrict__ q,
                                            float* __restrict__ k,
                                            float* __restrict__ yu16,
                                            int* __restrict__ gcnt) {
    int t = threadIdx.x;
    if (blockIdx.x < 16) yu16[blockIdx.x * 256 + t] = 0.0f;  // zero for k_pool atomics
    if (blockIdx.x == 0 && t < NR) gcnt[t] = 0;              // zero stream counters
    int w = t >> 6, lane = t & 63;
    int g = lane >> 4, seg = lane & 15;
    float4 wq4[4], wk4[4];
    #pragma unroll
    for (int j = 0; j < 4; ++j) {
        wq4[j] = ((const float4*)Wq)[seg + 16 * j];
        wk4[j] = ((const float4*)Wk)[seg + 16 * j];
    }
    float bqs = bq[0], bks = bk[0];
    int base = blockIdx.x * 64 + w * 16 + g;
    #pragma unroll
    for (int i = 0; i < 4; ++i) {
        int n = base + i * 4;
        if (n < N_NODES) {
            const float4* xr = (const float4*)(x + (size_t)n * CH);
            float dq = 0.0f, dk = 0.0f;
            #pragma unroll
            for (int j = 0; j < 4; ++j) {
                float4 xv = xr[seg + 16 * j];
                dq = fmaf(xv.x, wq4[j].x, fmaf(xv.y, wq4[j].y,
                     fmaf(xv.z, wq4[j].z, fmaf(xv.w, wq4[j].w, dq))));
                dk = fmaf(xv.x, wk4[j].x, fmaf(xv.y, wk4[j].y,
                     fmaf(xv.z, wk4[j].z, fmaf(xv.w, wk4[j].w, dk))));
            }
            dq += __shfl_down(dq, 8); dq += __shfl_down(dq, 4);
            dq += __shfl_down(dq, 2); dq += __shfl_down(dq, 1);
            dk += __shfl_down(dk, 8); dk += __shfl_down(dk, 4);
            dk += __shfl_down(dk, 2); dk += __shfl_down(dk, 1);
            if (seg == 0) { q[n] = dq + bqs; k[n] = dk + bks; }
        }
    }
}

// Single-pass partition with WAVE-AGGREGATED slotting: per 64-lane wave, 4 ballots,
// lane 0 does the only 4 LDS counter atomics (popcount each), bases broadcast by
// shfl, lanes compute rank from the ballot mask. 16x fewer counter atomics and no
// intra-wave serialization vs per-lane atomicAdd (R5's regression cause).
__global__ __launch_bounds__(1024) void k_part(const int* __restrict__ ei,
                                               const float* __restrict__ q,
                                               const float* __restrict__ k,
                                               int* __restrict__ gcnt,
                                               float* __restrict__ exs,
                                               unsigned short* __restrict__ rws) {
    extern __shared__ float lds[];
    float* lex = lds;                                          // [4*CAP] f32
    unsigned short* lrow = (unsigned short*)(lds + 4 * CAP);   // [4*CAP] u16
    int* cnt = (int*)(lds + 6 * CAP);                          // [4] counts, [4] gbase
    int t = threadIdx.x, lane = t & 63;
    unsigned long long ltmask = (1ULL << lane) - 1ULL;
    if (t < NR) cnt[t] = 0;
    __syncthreads();
    const int4* r4p = (const int4*)(ei) + blockIdx.x * (EPB_P / 4);
    const int4* c4p = (const int4*)(ei + N_EDGES) + blockIdx.x * (EPB_P / 4);
    for (int i4 = t; i4 < EPB_P / 4; i4 += 1024) {
        int4 rv = r4p[i4];
        int4 cv = c4p[i4];
        int rows[4] = {rv.x, rv.y, rv.z, rv.w};
        int cols[4] = {cv.x, cv.y, cv.z, cv.w};
        // hoist the 8 independent gathers ahead of the ballot chains
        float qe[4], ke[4];
        #pragma unroll
        for (int j = 0; j < 4; ++j) { qe[j] = q[rows[j]]; ke[j] = k[cols[j]]; }
        #pragma unroll
        for (int j = 0; j < 4; ++j) {
            int row = rows[j];
            int r = row / RANGE;               // magic-mul const div, r in 0..3
            float v = qe[j] * ke[j];
            float e = __expf(fmaxf(v, 0.2f * v));
            unsigned long long m0 = __ballot(r == 0);
            unsigned long long m1 = __ballot(r == 1);
            unsigned long long m2 = __ballot(r == 2);
            unsigned long long m3 = __ballot(r == 3);
            int b0 = 0, b1 = 0, b2 = 0, b3 = 0;
            if (lane == 0) {                   // one lane, 4 aggregated atomics
                b0 = atomicAdd(&cnt[0], __popcll(m0));
                b1 = atomicAdd(&cnt[1], __popcll(m1));
                b2 = atomicAdd(&cnt[2], __popcll(m2));
                b3 = atomicAdd(&cnt[3], __popcll(m3));
            }
            b0 = __shfl(b0, 0); b1 = __shfl(b1, 0);
            b2 = __shfl(b2, 0); b3 = __shfl(b3, 0);
            unsigned long long mr = (r == 0) ? m0 : (r == 1) ? m1 : (r == 2) ? m2 : m3;
            int br = (r == 0) ? b0 : (r == 1) ? b1 : (r == 2) ? b2 : b3;
            int slot = br + __popcll(mr & ltmask);
            lex[r * CAP + slot] = e;
            lrow[r * CAP + slot] = (unsigned short)(row - r * RANGE);
        }
    }
    __syncthreads();
    int* gbase = cnt + NR;
    if (t < NR) gbase[t] = atomicAdd(&gcnt[t], cnt[t]);
    __syncthreads();
    #pragma unroll
    for (int r = 0; r < NR; ++r) {
        int n = cnt[r], b = gbase[r];
        float* exd = exs + (size_t)r * SCAP + b;
        unsigned short* rwd = rws + (size_t)r * SCAP + b;
        const float* exsrc = lex + r * CAP;
        const unsigned short* rwsrc = lrow + r * CAP;
        for (int i = t; i < n; i += 1024) { exd[i] = exsrc[i]; rwd[i] = rwsrc[i]; }
    }
}

// Dense consumer: block (slice s, range r) streams its 1/SL chunk of range r's
// {e, rowlocal} stream (coalesced, 6 B/edge, exactly once), ds_add into a dense
// 100KB LDS accumulator, writes one dense partial slab. No gathers, no rescan.
__global__ __launch_bounds__(1024) void k_acc2(const float* __restrict__ exs,
                                               const unsigned short* __restrict__ rws,
                                               const int* __restrict__ gcnt,
                                               float* __restrict__ partial) {
    extern __shared__ float acc[];   // RANGE floats
    int t = threadIdx.x;
    int s = blockIdx.x >> 2, r = blockIdx.x & 3;
    for (int i = t; i < RANGE; i += 1024) acc[i] = 0.0f;
    __syncthreads();
    int n = gcnt[r];
    int per = (n + SL - 1) / SL;
    int i0 = s * per, i1 = min(i0 + per, n);
    const float* exr = exs + (size_t)r * SCAP;
    const unsigned short* rwr = rws + (size_t)r * SCAP;
    for (int i = i0 + t; i < i1; i += 1024)
        atomicAdd(&acc[rwr[i]], exr[i]);   // ds_add_f32, ~conflict-free (random over 25K)
    __syncthreads();
    float* dst = partial + ((size_t)r * SL + s) * RANGE;
    for (int i = t; i < RANGE; i += 1024) dst[i] = acc[i];
}

// Stage 2: awu[n] = sum_s partial[range(n)][s][n%RANGE]; ptot[blk] = block total partial
__global__ __launch_bounds__(256) void k_fold(const float* __restrict__ partial,
                                              float* __restrict__ awu,
                                              float* __restrict__ ptot) {
    int t = threadIdx.x;
    int n = blockIdx.x * 256 + t;
    float s = 0.0f;
    if (n < N_NODES) {
        int r = n / RANGE, off = n % RANGE;   // magic-mul div
        const float* p = partial + (size_t)r * SL * RANGE + off;
        #pragma unroll 8
        for (int g = 0; g < SL; ++g) s += p[(size_t)g * RANGE];
        awu[n] = s;
    }
    float rsum = s;
    #pragma unroll
    for (int off = 32; off; off >>= 1) rsum += __shfl_down(rsum, off);
    __shared__ float sm[4];
    if ((t & 63) == 0) sm[t >> 6] = rsum;
    __syncthreads();
    if (t == 0) ptot[blockIdx.x] = sm[0] + sm[1] + sm[2] + sm[3];
}

// total inline from ptot; yu16 atomic partials; aw_out = awu/total
__global__ __launch_bounds__(256) void k_pool(const float* __restrict__ x,
                                              const float* __restrict__ awu,
                                              const float* __restrict__ ptot,
                                              float* __restrict__ totalp,
                                              float* __restrict__ yu16,
                                              float* __restrict__ aw_out) {
    int t = threadIdx.x, s = t >> 6, g = t & 63;
    // reduce ptot[0..GP) -> total (every block, cheap)
    float ts = ptot[t] + ((t + 256 < GP) ? ptot[t + 256] : 0.0f);
    #pragma unroll
    for (int off = 32; off; off >>= 1) ts += __shfl_down(ts, off);
    __shared__ float sm[4];
    __shared__ float tot;
    if (g == 0) sm[s] = ts;
    __syncthreads();
    if (t == 0) {
        tot = sm[0] + sm[1] + sm[2] + sm[3];
        if (blockIdx.x == 0) totalp[0] = tot;
    }
    __syncthreads();
    float inv = 1.0f / tot;

    const float4* X4 = (const float4*)x;
    float4 acc = make_float4(0.f, 0.f, 0.f, 0.f);
    for (int base = blockIdx.x * 8; base < N_NODES; base += GRID_POOL * 8) {
        float a0 = awu[base + s];
        float a1 = awu[base + 4 + s];
        float4 x0 = X4[(size_t)(base + s) * 64 + g];
        float4 x1 = X4[(size_t)(base + 4 + s) * 64 + g];
        acc.x = fmaf(a0, x0.x, acc.x); acc.y = fmaf(a0, x0.y, acc.y);
        acc.z = fmaf(a0, x0.z, acc.z); acc.w = fmaf(a0, x0.w, acc.w);
        acc.x = fmaf(a1, x1.x, acc.x); acc.y = fmaf(a1, x1.y, acc.y);
        acc.z = fmaf(a1, x1.z, acc.z); acc.w = fmaf(a1, x1.w, acc.w);
    }
    __shared__ float4 tmp4[4][64];
    tmp4[s][g] = acc;
    __syncthreads();
    const float* tmp = (const float*)tmp4;
    float sum = tmp[0 * 256 + t] + tmp[1 * 256 + t] + tmp[2 * 256 + t] + tmp[3 * 256 + t];
    atomicAdd(&yu16[(blockIdx.x & (YCOPY - 1)) * 256 + t], sum);
    for (int i = blockIdx.x * 256 + t; i < N_NODES; i += GRID_POOL * 256)
        aw_out[i] = awu[i] * inv;
}

// grid 8: block j -> out[j*32 .. j*32+32)
__global__ __launch_bounds__(256) void k_final(const float* __restrict__ yu16,
                                               const float* __restrict__ totalp,
                                               const float* __restrict__ Wv,
                                               const float* __restrict__ bv,
                                               float* __restrict__ out) {
    __shared__ float ysh[256];
    __shared__ float red[256];
    int t = threadIdx.x;
    float inv = 1.0f / totalp[0];
    float yv = 0.0f;
    #pragma unroll
    for (int j = 0; j < YCOPY; ++j) yv += yu16[j * 256 + t];
    ysh[t] = yv * inv;
    __syncthreads();
    int c = blockIdx.x * 32 + (t & 31), rg = t >> 5;
    float acc = 0.0f;
    #pragma unroll
    for (int j = 0; j < 32; ++j) {
        int kk = rg * 32 + j;
        acc = fmaf(ysh[kk], Wv[(size_t)kk * CH + c], acc);
    }
    red[t] = acc;
    __syncthreads();
    if (t < 32) {
        float sv = 0.0f;
        #pragma unroll
        for (int j = 0; j < 8; ++j) sv += red[j * 32 + t];
        out[blockIdx.x * 32 + t] = sv + bv[blockIdx.x * 32 + t];
    }
}

extern "C" void kernel_launch(void* const* d_in, const int* in_sizes, int n_in,
                              void* d_out, int out_size, void* d_ws, size_t ws_size,
                              hipStream_t stream) {
    const float* x  = (const float*)d_in[0];
    const int*   ei = (const int*)d_in[1];
    const float* Wq = (const float*)d_in[2];
    const float* bq = (const float*)d_in[3];
    const float* Wk = (const float*)d_in[4];
    const float* bk = (const float*)d_in[5];
    const float* Wv = (const float*)d_in[6];
    const float* bv = (const float*)d_in[7];
    float* out = (float*)d_out;
    float* ws  = (float*)d_ws;

    float*          totalp  = ws + OFF_TOTAL;
    float*          ptot    = ws + OFF_PTOT;
    float*          yu16    = ws + OFF_YU16;
    int*            gcnt    = (int*)(ws + OFF_GCNT);
    float*          q       = ws + OFF_Q;
    float*          k       = ws + OFF_K;
    float*          awu     = ws + OFF_AWU;
    float*          exs     = ws + OFF_EXS;
    unsigned short* rws     = (unsigned short*)(ws + OFF_RWS);
    float*          partial = ws + OFF_PART;

    // one-time host-side attributes: allow >64KB dynamic LDS (not stream ops)
    static bool lds_init = false;
    if (!lds_init) {
        (void)hipFuncSetAttribute((const void*)k_part,
                                  hipFuncAttributeMaxDynamicSharedMemorySize,
                                  LDSP_BYTES);
        (void)hipFuncSetAttribute((const void*)k_acc2,
                                  hipFuncAttributeMaxDynamicSharedMemorySize,
                                  LDSA_BYTES);
        lds_init = true;
    }

    hipLaunchKernelGGL(k_qk, dim3(GRID_QK), dim3(256), 0, stream,
                       x, Wq, bq, Wk, bk, q, k, yu16, gcnt);
    hipLaunchKernelGGL(k_part, dim3(GRID_P), dim3(1024), LDSP_BYTES, stream,
                       ei, q, k, gcnt, exs, rws);
    hipLaunchKernelGGL(k_acc2, dim3(NR * SL), dim3(1024), LDSA_BYTES, stream,
                       exs, rws, gcnt, partial);
    hipLaunchKernelGGL(k_fold, dim3(GP), dim3(256), 0, stream,
                       partial, awu, ptot);
    hipLaunchKernelGGL(k_pool, dim3(GRID_POOL), dim3(256), 0, stream,
                       x, awu, ptot, totalp, yu16, out + CH);
    hipLaunchKernelGGL(k_final, dim3(8), dim3(256), 0, stream,
                       yu16, totalp, Wv, bv, out);
}

// Round 7
// 245.253 us; speedup vs baseline: 1.0567x; 1.0567x over previous
//
#include <hip/hip_runtime.h>

#define N_NODES 100000
#define N_EDGES 3200000
#define CH 256

#define GRID_QK 1563     // 64 nodes/block
#define GRID_POOL 512
#define YCOPY 16

// segmented-sum geometry: 8 node-ranges x 64 edge-slices, XCD-cohort swizzled
#define NR 8
#define RANGE 12500      // nodes per range; LDS acc = 50 KB static -> 2 blocks/CU
#define SL 64            // edge slices
#define EPS 50000        // edges per slice = N_EDGES / SL (exact)
#define QEPS 12500       // EPS/4 int4 loads per slice
#define GP 391           // ceil(N_NODES/256) fold blocks -> ptot entries

// ---- ws layout (float offsets) ----
#define OFF_TOTAL 0
#define OFF_PTOT  16       // 512 (only GP used)
#define OFF_YU16  528      // 4096
#define OFF_Q     4624     // 100000
#define OFF_K     104624   // 100000
#define OFF_AWU   204624   // 100000
#define OFF_PART  304624   // NR*SL*RANGE = 6,400,000 floats (25.6 MB)
// end = 6,704,624 floats ~= 26.8 MiB (ws ~= 400 MB per fill counters)

// q[n]=x[n,:].Wq+bq, k[n]=x[n,:].Wk+bk. 16-lane dot groups, 4 shuffle levels.
__global__ __launch_bounds__(256) void k_qk(const float* __restrict__ x,
                                            const float* __restrict__ Wq,
                                            const float* __restrict__ bq,
                                            const float* __restrict__ Wk,
                                            const float* __restrict__ bk,
                                            float* __restrict__ q,
                                            float* __restrict__ k,
                                            float* __restrict__ yu16) {
    int t = threadIdx.x;
    if (blockIdx.x < 16) yu16[blockIdx.x * 256 + t] = 0.0f;  // zero for k_pool atomics
    int w = t >> 6, lane = t & 63;
    int g = lane >> 4, seg = lane & 15;
    float4 wq4[4], wk4[4];
    #pragma unroll
    for (int j = 0; j < 4; ++j) {
        wq4[j] = ((const float4*)Wq)[seg + 16 * j];
        wk4[j] = ((const float4*)Wk)[seg + 16 * j];
    }
    float bqs = bq[0], bks = bk[0];
    int base = blockIdx.x * 64 + w * 16 + g;
    #pragma unroll
    for (int i = 0; i < 4; ++i) {
        int n = base + i * 4;
        if (n < N_NODES) {
            const float4* xr = (const float4*)(x + (size_t)n * CH);
            float dq = 0.0f, dk = 0.0f;
            #pragma unroll
            for (int j = 0; j < 4; ++j) {
                float4 xv = xr[seg + 16 * j];
                dq = fmaf(xv.x, wq4[j].x, fmaf(xv.y, wq4[j].y,
                     fmaf(xv.z, wq4[j].z, fmaf(xv.w, wq4[j].w, dq))));
                dk = fmaf(xv.x, wk4[j].x, fmaf(xv.y, wk4[j].y,
                     fmaf(xv.z, wk4[j].z, fmaf(xv.w, wk4[j].w, dk))));
            }
            dq += __shfl_down(dq, 8); dq += __shfl_down(dq, 4);
            dq += __shfl_down(dq, 2); dq += __shfl_down(dq, 1);
            dk += __shfl_down(dk, 8); dk += __shfl_down(dk, 4);
            dk += __shfl_down(dk, 2); dk += __shfl_down(dk, 1);
            if (seg == 0) { q[n] = dq + bqs; k[n] = dk + bks; }
        }
    }
}

// Segmented sum, stage 1. Block (slice s, range r) scans slice s's edges (int4
// rows AND int4 cols, fully coalesced), keeps rows in [r*RANGE,(r+1)*RANGE),
// gathers q/k (L2-resident), leaky+exp, ds_add_f32 into a 50KB LDS accumulator,
// writes one dense partial slab.
// XCD-cohort swizzle: all 8 range-blocks of a slice share bid%8, hence (by the
// bid%8->XCD round-robin heuristic) one XCD's L2 -> the 8x row/col rescan is
// served by L2 instead of L3/HBM (R3 measured FETCH=101MB=8x12.8MB without this).
// Mapping is a performance heuristic only: any bid->(s,r) bijection is correct.
__global__ __launch_bounds__(1024) void k_acc(const int* __restrict__ ei,
                                              const float* __restrict__ q,
                                              const float* __restrict__ k,
                                              float* __restrict__ partial) {
    __shared__ float acc[RANGE];   // 50,000 B static LDS -> 2 blocks/CU
    int t = threadIdx.x;
    int xcd = blockIdx.x & 7;
    int inner = blockIdx.x >> 3;        // 0..63
    int r = inner & 7;                  // range 0..7
    int s = (inner >> 3) * 8 + xcd;     // slice 0..63; s%8 == xcd
    for (int i = t; i < RANGE; i += 1024) acc[i] = 0.0f;
    __syncthreads();
    int r0 = r * RANGE;
    const int4* r4p = (const int4*)ei + s * QEPS;
    const int4* c4p = (const int4*)(ei + N_EDGES) + s * QEPS;
    for (int i4 = t; i4 < QEPS; i4 += 1024) {
        int4 rv = r4p[i4];
        int4 cv = c4p[i4];                 // coalesced 16B (was 4 predicated scalars)
        unsigned o0 = (unsigned)(rv.x - r0);
        unsigned o1 = (unsigned)(rv.y - r0);
        unsigned o2 = (unsigned)(rv.z - r0);
        unsigned o3 = (unsigned)(rv.w - r0);
        if (o0 < RANGE) {
            float v = q[rv.x] * k[cv.x];
            atomicAdd(&acc[o0], __expf(fmaxf(v, 0.2f * v)));   // ds_add_f32
        }
        if (o1 < RANGE) {
            float v = q[rv.y] * k[cv.y];
            atomicAdd(&acc[o1], __expf(fmaxf(v, 0.2f * v)));
        }
        if (o2 < RANGE) {
            float v = q[rv.z] * k[cv.z];
            atomicAdd(&acc[o2], __expf(fmaxf(v, 0.2f * v)));
        }
        if (o3 < RANGE) {
            float v = q[rv.w] * k[cv.w];
            atomicAdd(&acc[o3], __expf(fmaxf(v, 0.2f * v)));
        }
    }
    __syncthreads();
    float* dst = partial + ((size_t)r * SL + s) * RANGE;
    for (int i = t; i < RANGE; i += 1024) dst[i] = acc[i];
}

// Stage 2: awu[n] = sum_s partial[range(n)][s][n%RANGE]; ptot[blk] = block total partial
__global__ __launch_bounds__(256) void k_fold(const float* __restrict__ partial,
                                              float* __restrict__ awu,
                                              float* __restrict__ ptot) {
    int t = threadIdx.x;
    int n = blockIdx.x * 256 + t;
    float s = 0.0f;
    if (n < N_NODES) {
        int r = n / RANGE, off = n % RANGE;   // magic-mul div
        const float* p = partial + (size_t)r * SL * RANGE + off;
        #pragma unroll 8
        for (int g = 0; g < SL; ++g) s += p[(size_t)g * RANGE];
        awu[n] = s;
    }
    float rsum = s;
    #pragma unroll
    for (int off = 32; off; off >>= 1) rsum += __shfl_down(rsum, off);
    __shared__ float sm[4];
    if ((t & 63) == 0) sm[t >> 6] = rsum;
    __syncthreads();
    if (t == 0) ptot[blockIdx.x] = sm[0] + sm[1] + sm[2] + sm[3];
}

// total inline from ptot; yu16 atomic partials; aw_out = awu/total
__global__ __launch_bounds__(256) void k_pool(const float* __restrict__ x,
                                              const float* __restrict__ awu,
                                              const float* __restrict__ ptot,
                                              float* __restrict__ totalp,
                                              float* __restrict__ yu16,
                                              float* __restrict__ aw_out) {
    int t = threadIdx.x, s = t >> 6, g = t & 63;
    // reduce ptot[0..GP) -> total (every block, cheap)
    float ts = ptot[t] + ((t + 256 < GP) ? ptot[t + 256] : 0.0f);
    #pragma unroll
    for (int off = 32; off; off >>= 1) ts += __shfl_down(ts, off);
    __shared__ float sm[4];
    __shared__ float tot;
    if (g == 0) sm[s] = ts;
    __syncthreads();
    if (t == 0) {
        tot = sm[0] + sm[1] + sm[2] + sm[3];
        if (blockIdx.x == 0) totalp[0] = tot;
    }
    __syncthreads();
    float inv = 1.0f / tot;

    const float4* X4 = (const float4*)x;
    float4 acc = make_float4(0.f, 0.f, 0.f, 0.f);
    for (int base = blockIdx.x * 8; base < N_NODES; base += GRID_POOL * 8) {
        float a0 = awu[base + s];
        float a1 = awu[base + 4 + s];
        float4 x0 = X4[(size_t)(base + s) * 64 + g];
        float4 x1 = X4[(size_t)(base + 4 + s) * 64 + g];
        acc.x = fmaf(a0, x0.x, acc.x); acc.y = fmaf(a0, x0.y, acc.y);
        acc.z = fmaf(a0, x0.z, acc.z); acc.w = fmaf(a0, x0.w, acc.w);
        acc.x = fmaf(a1, x1.x, acc.x); acc.y = fmaf(a1, x1.y, acc.y);
        acc.z = fmaf(a1, x1.z, acc.z); acc.w = fmaf(a1, x1.w, acc.w);
    }
    __shared__ float4 tmp4[4][64];
    tmp4[s][g] = acc;
    __syncthreads();
    const float* tmp = (const float*)tmp4;
    float sum = tmp[0 * 256 + t] + tmp[1 * 256 + t] + tmp[2 * 256 + t] + tmp[3 * 256 + t];
    atomicAdd(&yu16[(blockIdx.x & (YCOPY - 1)) * 256 + t], sum);
    for (int i = blockIdx.x * 256 + t; i < N_NODES; i += GRID_POOL * 256)
        aw_out[i] = awu[i] * inv;
}

// grid 8: block j -> out[j*32 .. j*32+32)
__global__ __launch_bounds__(256) void k_final(const float* __restrict__ yu16,
                                               const float* __restrict__ totalp,
                                               const float* __restrict__ Wv,
                                               const float* __restrict__ bv,
                                               float* __restrict__ out) {
    __shared__ float ysh[256];
    __shared__ float red[256];
    int t = threadIdx.x;
    float inv = 1.0f / totalp[0];
    float yv = 0.0f;
    #pragma unroll
    for (int j = 0; j < YCOPY; ++j) yv += yu16[j * 256 + t];
    ysh[t] = yv * inv;
    __syncthreads();
    int c = blockIdx.x * 32 + (t & 31), rg = t >> 5;
    float acc = 0.0f;
    #pragma unroll
    for (int j = 0; j < 32; ++j) {
        int kk = rg * 32 + j;
        acc = fmaf(ysh[kk], Wv[(size_t)kk * CH + c], acc);
    }
    red[t] = acc;
    __syncthreads();
    if (t < 32) {
        float sv = 0.0f;
        #pragma unroll
        for (int j = 0; j < 8; ++j) sv += red[j * 32 + t];
        out[blockIdx.x * 32 + t] = sv + bv[blockIdx.x * 32 + t];
    }
}

extern "C" void kernel_launch(void* const* d_in, const int* in_sizes, int n_in,
                              void* d_out, int out_size, void* d_ws, size_t ws_size,
                              hipStream_t stream) {
    const float* x  = (const float*)d_in[0];
    const int*   ei = (const int*)d_in[1];
    const float* Wq = (const float*)d_in[2];
    const float* bq = (const float*)d_in[3];
    const float* Wk = (const float*)d_in[4];
    const float* bk = (const float*)d_in[5];
    const float* Wv = (const float*)d_in[6];
    const float* bv = (const float*)d_in[7];
    float* out = (float*)d_out;
    float* ws  = (float*)d_ws;

    float* totalp  = ws + OFF_TOTAL;
    float* ptot    = ws + OFF_PTOT;
    float* yu16    = ws + OFF_YU16;
    float* q       = ws + OFF_Q;
    float* k       = ws + OFF_K;
    float* awu     = ws + OFF_AWU;
    float* partial = ws + OFF_PART;

    hipLaunchKernelGGL(k_qk, dim3(GRID_QK), dim3(256), 0, stream,
                       x, Wq, bq, Wk, bk, q, k, yu16);
    hipLaunchKernelGGL(k_acc, dim3(NR * SL), dim3(1024), 0, stream,
                       ei, q, k, partial);
    hipLaunchKernelGGL(k_fold, dim3(GP), dim3(256), 0, stream,
                       partial, awu, ptot);
    hipLaunchKernelGGL(k_pool, dim3(GRID_POOL), dim3(256), 0, stream,
                       x, awu, ptot, totalp, yu16, out + CH);
    hipLaunchKernelGGL(k_final, dim3(8), dim3(256), 0, stream,
                       yu16, totalp, Wv, bv, out);
}